// Round 2
// baseline (1052.979 us; speedup 1.0000x reference)
//
#include <hip/hip_runtime.h>
#include <cstdint>
#include <cstddef>

#define BB 2
#define LL 1024
#define DM 768
#define DI 1536
#define NS 16
#define DTR 48
#define TEMB_ 1024

static __device__ __forceinline__ float sigmoidf_(float x){ return 1.f/(1.f+__expf(-x)); }
static __device__ __forceinline__ float siluf_(float x){ return x*sigmoidf_(x); }
static __device__ __forceinline__ float softplusf_(float x){ return (x>15.f)? x : log1pf(__expf(x)); }

// ---------- cross-lane helpers: pure-VALU DPP, 16-lane groups ----------
// ctrl: quad_perm 0xB1 = xor1, quad_perm 0x4E = xor2,
//       row_half_mirror 0x141 = xor7, row_mirror 0x140 = xor15.
#define DPPX(CTRL, x) __int_as_float(__builtin_amdgcn_update_dpp(0, __float_as_int(x), (CTRL), 0xF, 0xF, true))

// full 16-lane all-reduce sum (valid butterfly: after xor1+xor2 all lanes in a
// quad are equal, so xor7 == flip bit2 and xor15 == flip bit3)
static __device__ __forceinline__ float sum16(float x){
  x += DPPX(0xB1, x);
  x += DPPX(0x4E, x);
  x += DPPX(0x141, x);
  x += DPPX(0x140, x);
  return x;
}

// ---------- K0: emb path:  eo[b][j] = silu(emb[b]) . We[j] + be[j] ----------
__global__ __launch_bounds__(128) void emb_kernel(const float* __restrict__ emb,
                                                  const float* __restrict__ We,
                                                  const float* __restrict__ be,
                                                  float* __restrict__ eo){
  __shared__ float se[TEMB_];
  const int b = blockIdx.x / 12;
  const int jb = (blockIdx.x % 12) * 128;
  for (int i = threadIdx.x; i < TEMB_; i += 128) se[i] = siluf_(emb[b*TEMB_ + i]);
  __syncthreads();
  const int j = jb + threadIdx.x;
  const float* wr = We + (size_t)j * TEMB_;
  float acc = 0.f;
  #pragma unroll 4
  for (int k = 0; k < TEMB_; k += 4){
    acc = fmaf(se[k+0], wr[k+0], acc);
    acc = fmaf(se[k+1], wr[k+1], acc);
    acc = fmaf(se[k+2], wr[k+2], acc);
    acc = fmaf(se[k+3], wr[k+3], acc);
  }
  eo[b*(2*DM) + j] = acc + be[j];
}

// ---------- K1: RMSNorm  xn = x * rsqrt(mean(x^2)+1e-5) * w ----------
__global__ __launch_bounds__(256) void rmsnorm_kernel(const float* __restrict__ x,
                                                      const float* __restrict__ w,
                                                      float* __restrict__ xn){
  const int row = blockIdx.x;
  const int tid = threadIdx.x;
  const float* xp = x + (size_t)row * DM;
  float vals[3];
  float p = 0.f;
  #pragma unroll
  for (int i = 0; i < 3; i++){ float v = xp[tid + i*256]; vals[i] = v; p += v*v; }
  #pragma unroll
  for (int off = 32; off; off >>= 1) p += __shfl_xor(p, off);
  __shared__ float wsum[4];
  if ((tid & 63) == 0) wsum[tid >> 6] = p;
  __syncthreads();
  float total = wsum[0] + wsum[1] + wsum[2] + wsum[3];
  float rs = rsqrtf(total * (1.f/768.f) + 1e-5f);
  #pragma unroll
  for (int i = 0; i < 3; i++){ int j = tid + i*256; xn[(size_t)row*DM + j] = vals[i]*rs*w[j]; }
}

// ---------- K2: depthwise causal conv (k=4) + bias + SiLU ----------
__global__ __launch_bounds__(256) void conv_silu_kernel(const float* __restrict__ xr,
                                                        const float* __restrict__ cw,
                                                        const float* __restrict__ cb,
                                                        float* __restrict__ uc){
  const int d  = blockIdx.x*256 + threadIdx.x;   // grid.x = 6
  const int bt = blockIdx.y;                     // 0..2047
  const int t  = bt & (LL-1);
  const float w0 = cw[d*4+0], w1 = cw[d*4+1], w2 = cw[d*4+2], w3 = cw[d*4+3];
  const float* up = xr + (size_t)bt*(2*DI) + d;  // u[bt][d], row stride 3072
  float s = cb[d];
  if (t >= 3) s = fmaf(up[-3*2*DI], w0, s);
  if (t >= 2) s = fmaf(up[-2*2*DI], w1, s);
  if (t >= 1) s = fmaf(up[-1*2*DI], w2, s);
  s = fmaf(up[0], w3, s);
  uc[(size_t)bt*DI + d] = siluf_(s);
}

// ---------- generic fp32 tiled GEMM:  C[M,N] = A[M,K] * B[N,K]^T  ----------
// EPI: 0 = none ; 1 = softplus(acc + bias) ; 2 = acc + bias + resid
template<int EPI>
__global__ __launch_bounds__(256) void gemm_nt(const float* __restrict__ A, int lda,
                                               const float* __restrict__ B, int ldb,
                                               float* __restrict__ C, int ldc,
                                               int N, int K,
                                               const float* __restrict__ bias,
                                               const float* __restrict__ resid){
  __shared__ float As[16][68];
  __shared__ float Bs[16][68];
  const int tid = threadIdx.x;
  const int m0 = blockIdx.y * 64;
  const int n0 = blockIdx.x * 64;
  const int lr = tid >> 2;        // 0..63 row within tile
  const int lk = (tid & 3) << 2;  // 0,4,8,12
  const int tx = tid & 15;        // n quad
  const int ty = tid >> 4;        // m quad
  float acc[4][4] = {};
  for (int k0 = 0; k0 < K; k0 += 16){
    float4 ga = *(const float4*)(A + (size_t)(m0 + lr)*lda + k0 + lk);
    float4 gb;
    if (n0 + lr < N) gb = *(const float4*)(B + (size_t)(n0 + lr)*ldb + k0 + lk);
    else             gb = make_float4(0.f,0.f,0.f,0.f);
    __syncthreads();
    As[lk+0][lr] = ga.x; As[lk+1][lr] = ga.y; As[lk+2][lr] = ga.z; As[lk+3][lr] = ga.w;
    Bs[lk+0][lr] = gb.x; Bs[lk+1][lr] = gb.y; Bs[lk+2][lr] = gb.z; Bs[lk+3][lr] = gb.w;
    __syncthreads();
    #pragma unroll
    for (int k = 0; k < 16; k++){
      float4 av = *(const float4*)&As[k][ty*4];
      float4 bv = *(const float4*)&Bs[k][tx*4];
      float a4[4] = {av.x, av.y, av.z, av.w};
      float b4[4] = {bv.x, bv.y, bv.z, bv.w};
      #pragma unroll
      for (int i = 0; i < 4; i++)
        #pragma unroll
        for (int j = 0; j < 4; j++)
          acc[i][j] = fmaf(a4[i], b4[j], acc[i][j]);
    }
  }
  #pragma unroll
  for (int i = 0; i < 4; i++){
    const int row = m0 + ty*4 + i;
    #pragma unroll
    for (int j = 0; j < 4; j++){
      const int col = n0 + tx*4 + j;
      if (col < N){
        float r = acc[i][j];
        if constexpr (EPI == 1) r = softplusf_(r + bias[col]);
        if constexpr (EPI == 2) r = r + bias[col] + resid[(size_t)row*ldc + col];
        C[(size_t)row*ldc + col] = r;
      }
    }
  }
}

// ---------- K5: sequential selective-scan with LN/attention gate ----------
// 16 lanes per (b,d) chain; lane = state index n (also output index h).
// All cross-lane via DPP (no LDS). Matvec via Gray-code xor walk:
//   g = {0,1,3,2,5,4,6,7,8,9,11,10,13,12,14,15}; transitions in {1,2,7,15}.
__global__ __launch_bounds__(256) void scan_kernel(const float* __restrict__ delta,
                                                   const float* __restrict__ uc,
                                                   const float* __restrict__ xr,    // res at col offset DI
                                                   const float* __restrict__ x_dbl, // (2048,80)
                                                   const float* __restrict__ A_log,
                                                   const float* __restrict__ Dp,
                                                   const float* __restrict__ Wq,
                                                   const float* __restrict__ Wk,
                                                   const float* __restrict__ Wv,
                                                   const float* __restrict__ g_s, const float* __restrict__ b_s,
                                                   const float* __restrict__ g_c, const float* __restrict__ b_c,
                                                   float* __restrict__ y){
  const int lane  = threadIdx.x & 15;
  const int chain = threadIdx.x >> 4;            // 0..15
  const int d = blockIdx.x * 16 + chain;         // grid.x = 96
  const int b = blockIdx.y;                      // grid.y = 2

  // Gray walk over columns; wq[i] = Wq[lane][lane ^ g[i]]
  constexpr int gseq[16] = {0,1,3,2,5,4,6,7,8,9,11,10,13,12,14,15};
  float wq[16], wk[16], wv[16];
  #pragma unroll
  for (int i = 0; i < 16; i++){
    const int c = lane ^ gseq[i];
    wq[i] = Wq[lane*16 + c];
    wk[i] = Wk[lane*16 + c];
    wv[i] = Wv[lane*16 + c];
  }
  const float A_dn = -__expf(A_log[d*16 + lane]);
  const float gs = g_s[lane], bs0 = b_s[lane];
  const float gc = g_c[lane], bc0 = b_c[lane];
  const float Dpd = Dp[d];

  const float* dptr = delta + (size_t)b*LL*DI + d;
  const float* uptr = uc    + (size_t)b*LL*DI + d;
  const float* rptr = xr    + (size_t)b*LL*(2*DI) + DI + d;
  const float* xb   = x_dbl + (size_t)b*LL*80;
  float* yptr = y + (size_t)b*LL*DI + d;

  float s = 0.f;

  // one step of the recurrence (pure VALU + DPP)
  #define MV(i, CTRL) { vs = DPPX(CTRL, vs); vc = DPPX(CTRL, vc); \
    qq = fmaf(vs, wq[i], qq); kk = fmaf(vc, wk[i], kk); vv = fmaf(vc, wv[i], vv); }
  #define STEP(tcur, dv, uv, rv, Bv, Cv) { \
    const float dA  = __expf((dv) * A_dn); \
    const float dBu = (dv) * (Bv) * (uv); \
    const float st  = dA * s; \
    float ssum = sum16(st); \
    float ssq  = sum16(st*st); \
    float m_s  = ssum * 0.0625f; \
    float v_s  = ssq  * 0.0625f - m_s*m_s; \
    float ln_s = (st - m_s) * rsqrtf(v_s + 1e-5f) * gs + bs0; \
    float csum = sum16(dBu); \
    float csq  = sum16(dBu*dBu); \
    float m_c  = csum * 0.0625f; \
    float v_c  = csq  * 0.0625f - m_c*m_c; \
    float ln_c = (dBu - m_c) * rsqrtf(v_c + 1e-5f) * gc + bc0; \
    float vs = ln_s, vc = ln_c; \
    float qq = vs*wq[0], kk = vc*wk[0], vv = vc*wv[0]; \
    MV(1,0xB1)  MV(2,0x4E)  MV(3,0xB1)  MV(4,0x141) \
    MV(5,0xB1)  MV(6,0x4E)  MV(7,0xB1)  MV(8,0x140) \
    MV(9,0xB1)  MV(10,0x4E) MV(11,0xB1) MV(12,0x141) \
    MV(13,0xB1) MV(14,0x4E) MV(15,0xB1) \
    const float wgt = sum16(qq*kk) * 0.25f; \
    const float nv  = (1.f - wgt)*qq + wgt*vv; \
    s = nv; \
    const float yv = sum16(nv * (Cv)); \
    if (lane == 0) yptr[(size_t)(tcur)*DI] = (yv + (uv)*Dpd) * siluf_(rv); \
  }

  // prefetch depth 4: load t0+4..t0+7 at top of each 4-step group
  float cd[4], cu[4], cr[4], cB[4], cC[4];
  #pragma unroll
  for (int i = 0; i < 4; i++){
    cd[i] = dptr[(size_t)i*DI];
    cu[i] = uptr[(size_t)i*DI];
    cr[i] = rptr[(size_t)i*(2*DI)];
    cB[i] = xb[i*80 + 48 + lane];
    cC[i] = xb[i*80 + 64 + lane];
  }
  for (int t0 = 0; t0 < LL; t0 += 4){
    float nd[4], nu[4], nr[4], nB[4], nC[4];
    const int tn = t0 + 4;
    if (tn < LL){
      #pragma unroll
      for (int i = 0; i < 4; i++){
        const int t = tn + i;
        nd[i] = dptr[(size_t)t*DI];
        nu[i] = uptr[(size_t)t*DI];
        nr[i] = rptr[(size_t)t*(2*DI)];
        nB[i] = xb[t*80 + 48 + lane];
        nC[i] = xb[t*80 + 64 + lane];
      }
    } else {
      #pragma unroll
      for (int i = 0; i < 4; i++){ nd[i]=0.f; nu[i]=0.f; nr[i]=0.f; nB[i]=0.f; nC[i]=0.f; }
    }
    STEP(t0+0, cd[0], cu[0], cr[0], cB[0], cC[0])
    STEP(t0+1, cd[1], cu[1], cr[1], cB[1], cC[1])
    STEP(t0+2, cd[2], cu[2], cr[2], cB[2], cC[2])
    STEP(t0+3, cd[3], cu[3], cr[3], cB[3], cC[3])
    #pragma unroll
    for (int i = 0; i < 4; i++){ cd[i]=nd[i]; cu[i]=nu[i]; cr[i]=nr[i]; cB[i]=nB[i]; cC[i]=nC[i]; }
  }
  #undef STEP
  #undef MV
}

// ---------- K6: LN(h) * (1+scale) + shift, then SiLU (in place) ----------
__global__ __launch_bounds__(256) void lnmod_kernel(float* __restrict__ h,
                                                    const float* __restrict__ g,
                                                    const float* __restrict__ bb,
                                                    const float* __restrict__ eo){
  const int row = blockIdx.x;
  const int b = row >> 10;
  float* hp = h + (size_t)row * DM;
  const int tid = threadIdx.x;
  float vals[3];
  float s1 = 0.f, s2 = 0.f;
  #pragma unroll
  for (int i = 0; i < 3; i++){ float v = hp[tid + i*256]; vals[i] = v; s1 += v; s2 += v*v; }
  #pragma unroll
  for (int off = 32; off; off >>= 1){ s1 += __shfl_xor(s1, off); s2 += __shfl_xor(s2, off); }
  __shared__ float wa[4], wb[4];
  if ((tid & 63) == 0){ wa[tid >> 6] = s1; wb[tid >> 6] = s2; }
  __syncthreads();
  s1 = wa[0] + wa[1] + wa[2] + wa[3];
  s2 = wb[0] + wb[1] + wb[2] + wb[3];
  const float m  = s1 * (1.f/768.f);
  const float var = s2 * (1.f/768.f) - m*m;
  const float rs = rsqrtf(var + 1e-5f);
  #pragma unroll
  for (int i = 0; i < 3; i++){
    const int j = tid + i*256;
    float h2 = (vals[i] - m)*rs*g[j] + bb[j];
    const float sc = eo[b*(2*DM) + j];
    const float sh = eo[b*(2*DM) + DM + j];
    h2 = h2*(1.f + sc) + sh;
    hp[j] = siluf_(h2);
  }
}

extern "C" void kernel_launch(void* const* d_in, const int* in_sizes, int n_in,
                              void* d_out, int out_size, void* d_ws, size_t ws_size,
                              hipStream_t stream){
  const float* x      = (const float*)d_in[0];
  const float* emb    = (const float*)d_in[1];
  const float* rms_w  = (const float*)d_in[2];
  const float* Win    = (const float*)d_in[3];
  const float* conv_w = (const float*)d_in[4];
  const float* conv_b = (const float*)d_in[5];
  const float* Wx     = (const float*)d_in[6];
  const float* Wdt    = (const float*)d_in[7];
  const float* bdt    = (const float*)d_in[8];
  const float* A_log  = (const float*)d_in[9];
  const float* Dp     = (const float*)d_in[10];
  const float* Wout   = (const float*)d_in[11];
  const float* Wq     = (const float*)d_in[12];
  const float* Wk     = (const float*)d_in[13];
  const float* Wv     = (const float*)d_in[14];
  const float* ln_s_g = (const float*)d_in[15];
  const float* ln_s_b = (const float*)d_in[16];
  const float* ln_c_g = (const float*)d_in[17];
  const float* ln_c_b = (const float*)d_in[18];
  const float* We     = (const float*)d_in[19];
  const float* be     = (const float*)d_in[20];
  const float* ln_h_g = (const float*)d_in[21];
  const float* ln_h_b = (const float*)d_in[22];
  const float* Wo     = (const float*)d_in[23];
  const float* bo     = (const float*)d_in[24];
  float* out = (float*)d_out;

  float* ws  = (float*)d_ws;
  float* xr  = ws;                        // 2048*3072
  float* ucb = xr  + (size_t)2048*3072;   // 2048*1536
  float* xdb = ucb + (size_t)2048*1536;   // 2048*80
  float* dlt = xdb + (size_t)2048*80;     // 2048*1536
  float* yb  = dlt + (size_t)2048*1536;   // 2048*1536
  float* xnh = yb  + (size_t)2048*1536;   // 2048*768 (xn, later h/s2)
  float* eo  = xnh + (size_t)2048*768;    // 2*1536

  // emb path (independent)
  emb_kernel<<<24, 128, 0, stream>>>(emb, We, be, eo);
  // RMSNorm
  rmsnorm_kernel<<<2048, 256, 0, stream>>>(x, rms_w, xnh);
  // xr = xn @ Win^T   (2048 x 3072, K=768)
  gemm_nt<0><<<dim3(48, 32), 256, 0, stream>>>(xnh, DM, Win, DM, xr, 2*DI, 2*DI, DM, nullptr, nullptr);
  // uc = silu(causal depthwise conv(u) + cb)
  conv_silu_kernel<<<dim3(6, 2048), 256, 0, stream>>>(xr, conv_w, conv_b, ucb);
  // x_dbl = uc @ Wx^T  (2048 x 80, K=1536)
  gemm_nt<0><<<dim3(2, 32), 256, 0, stream>>>(ucb, DI, Wx, DI, xdb, 80, 80, DI, nullptr, nullptr);
  // delta = softplus(x_dbl[:, :48] @ Wdt^T + bdt)  (2048 x 1536, K=48)
  gemm_nt<1><<<dim3(24, 32), 256, 0, stream>>>(xdb, 80, Wdt, DTR, dlt, DI, DI, DTR, bdt, nullptr);
  // sequential scan -> y (fused with +uc*Dp and *silu(res))
  scan_kernel<<<dim3(96, 2), 256, 0, stream>>>(dlt, ucb, xr, xdb, A_log, Dp, Wq, Wk, Wv,
                                               ln_s_g, ln_s_b, ln_c_g, ln_c_b, yb);
  // h = y @ Wout^T  (2048 x 768, K=1536)
  gemm_nt<0><<<dim3(12, 32), 256, 0, stream>>>(yb, DI, Wout, DI, xnh, DM, DM, DI, nullptr, nullptr);
  // h2 = LN(h)*(1+scale)+shift ; s2 = silu(h2)  (in-place)
  lnmod_kernel<<<2048, 256, 0, stream>>>(xnh, ln_h_g, ln_h_b, eo);
  // out = x + s2 @ Wo^T + bo
  gemm_nt<2><<<dim3(12, 32), 256, 0, stream>>>(xnh, DM, Wo, DM, out, DM, DM, DM, bo, x);
}

// Round 3
// 854.680 us; speedup vs baseline: 1.2320x; 1.2320x over previous
//
#include <hip/hip_runtime.h>
#include <cstdint>
#include <cstddef>

#define BB 2
#define LL 1024
#define DM 768
#define DI 1536
#define NS 16
#define DTR 48
#define TEMB_ 1024
#define WSPAD 16   // padded rows after streamed arrays so scan prefetch never branches

static __device__ __forceinline__ float sigmoidf_(float x){ return 1.f/(1.f+__expf(-x)); }
static __device__ __forceinline__ float siluf_(float x){ return x*sigmoidf_(x); }
static __device__ __forceinline__ float softplusf_(float x){ return (x>15.f)? x : log1pf(__expf(x)); }

// ---------- cross-lane helpers: pure-VALU DPP, 16-lane groups ----------
// quad_perm 0xB1 = xor1, quad_perm 0x4E = xor2,
// row_half_mirror 0x141 = xor7, row_mirror 0x140 = xor15.
#define DPPX(CTRL, x) __int_as_float(__builtin_amdgcn_update_dpp(0, __float_as_int(x), (CTRL), 0xF, 0xF, true))

static __device__ __forceinline__ float sum16(float x){
  x += DPPX(0xB1, x);
  x += DPPX(0x4E, x);
  x += DPPX(0x141, x);
  x += DPPX(0x140, x);
  return x;
}

// ---------- K0: emb path:  eo[b][j] = silu(emb[b]) . We[j] + be[j] ----------
__global__ __launch_bounds__(128) void emb_kernel(const float* __restrict__ emb,
                                                  const float* __restrict__ We,
                                                  const float* __restrict__ be,
                                                  float* __restrict__ eo){
  __shared__ float se[TEMB_];
  const int b = blockIdx.x / 12;
  const int jb = (blockIdx.x % 12) * 128;
  for (int i = threadIdx.x; i < TEMB_; i += 128) se[i] = siluf_(emb[b*TEMB_ + i]);
  __syncthreads();
  const int j = jb + threadIdx.x;
  const float* wr = We + (size_t)j * TEMB_;
  float acc = 0.f;
  #pragma unroll 4
  for (int k = 0; k < TEMB_; k += 4){
    acc = fmaf(se[k+0], wr[k+0], acc);
    acc = fmaf(se[k+1], wr[k+1], acc);
    acc = fmaf(se[k+2], wr[k+2], acc);
    acc = fmaf(se[k+3], wr[k+3], acc);
  }
  eo[b*(2*DM) + j] = acc + be[j];
}

// ---------- K1: RMSNorm ----------
__global__ __launch_bounds__(256) void rmsnorm_kernel(const float* __restrict__ x,
                                                      const float* __restrict__ w,
                                                      float* __restrict__ xn){
  const int row = blockIdx.x;
  const int tid = threadIdx.x;
  const float* xp = x + (size_t)row * DM;
  float vals[3];
  float p = 0.f;
  #pragma unroll
  for (int i = 0; i < 3; i++){ float v = xp[tid + i*256]; vals[i] = v; p += v*v; }
  #pragma unroll
  for (int off = 32; off; off >>= 1) p += __shfl_xor(p, off);
  __shared__ float wsum[4];
  if ((tid & 63) == 0) wsum[tid >> 6] = p;
  __syncthreads();
  float total = wsum[0] + wsum[1] + wsum[2] + wsum[3];
  float rs = rsqrtf(total * (1.f/768.f) + 1e-5f);
  #pragma unroll
  for (int i = 0; i < 3; i++){ int j = tid + i*256; xn[(size_t)row*DM + j] = vals[i]*rs*w[j]; }
}

// ---------- K2: depthwise causal conv (k=4) + bias + SiLU ----------
__global__ __launch_bounds__(256) void conv_silu_kernel(const float* __restrict__ xr,
                                                        const float* __restrict__ cw,
                                                        const float* __restrict__ cb,
                                                        float* __restrict__ uc){
  const int d  = blockIdx.x*256 + threadIdx.x;
  const int bt = blockIdx.y;
  const int t  = bt & (LL-1);
  const float w0 = cw[d*4+0], w1 = cw[d*4+1], w2 = cw[d*4+2], w3 = cw[d*4+3];
  const float* up = xr + (size_t)bt*(2*DI) + d;
  float s = cb[d];
  if (t >= 3) s = fmaf(up[-3*2*DI], w0, s);
  if (t >= 2) s = fmaf(up[-2*2*DI], w1, s);
  if (t >= 1) s = fmaf(up[-1*2*DI], w2, s);
  s = fmaf(up[0], w3, s);
  uc[(size_t)bt*DI + d] = siluf_(s);
}

// ---------- generic fp32 tiled GEMM:  C[M,N] = A[M,K] * B[N,K]^T ----------
template<int EPI>
__global__ __launch_bounds__(256) void gemm_nt(const float* __restrict__ A, int lda,
                                               const float* __restrict__ B, int ldb,
                                               float* __restrict__ C, int ldc,
                                               int N, int K,
                                               const float* __restrict__ bias,
                                               const float* __restrict__ resid){
  __shared__ float As[16][68];
  __shared__ float Bs[16][68];
  const int tid = threadIdx.x;
  const int m0 = blockIdx.y * 64;
  const int n0 = blockIdx.x * 64;
  const int lr = tid >> 2;
  const int lk = (tid & 3) << 2;
  const int tx = tid & 15;
  const int ty = tid >> 4;
  float acc[4][4] = {};
  for (int k0 = 0; k0 < K; k0 += 16){
    float4 ga = *(const float4*)(A + (size_t)(m0 + lr)*lda + k0 + lk);
    float4 gb;
    if (n0 + lr < N) gb = *(const float4*)(B + (size_t)(n0 + lr)*ldb + k0 + lk);
    else             gb = make_float4(0.f,0.f,0.f,0.f);
    __syncthreads();
    As[lk+0][lr] = ga.x; As[lk+1][lr] = ga.y; As[lk+2][lr] = ga.z; As[lk+3][lr] = ga.w;
    Bs[lk+0][lr] = gb.x; Bs[lk+1][lr] = gb.y; Bs[lk+2][lr] = gb.z; Bs[lk+3][lr] = gb.w;
    __syncthreads();
    #pragma unroll
    for (int k = 0; k < 16; k++){
      float4 av = *(const float4*)&As[k][ty*4];
      float4 bv = *(const float4*)&Bs[k][tx*4];
      float a4[4] = {av.x, av.y, av.z, av.w};
      float b4[4] = {bv.x, bv.y, bv.z, bv.w};
      #pragma unroll
      for (int i = 0; i < 4; i++)
        #pragma unroll
        for (int j = 0; j < 4; j++)
          acc[i][j] = fmaf(a4[i], b4[j], acc[i][j]);
    }
  }
  #pragma unroll
  for (int i = 0; i < 4; i++){
    const int row = m0 + ty*4 + i;
    #pragma unroll
    for (int j = 0; j < 4; j++){
      const int col = n0 + tx*4 + j;
      if (col < N){
        float r = acc[i][j];
        if constexpr (EPI == 1) r = softplusf_(r + bias[col]);
        if constexpr (EPI == 2) r = r + bias[col] + resid[(size_t)row*ldc + col];
        C[(size_t)row*ldc + col] = r;
      }
    }
  }
}

// ---------- K3b: Bm row-stats  (mB, vB) per (b,t) ----------
__global__ __launch_bounds__(256) void bstat_kernel(const float* __restrict__ x_dbl,
                                                    float2* __restrict__ bs){
  const int row = blockIdx.x*256 + threadIdx.x;   // grid 8 -> 2048 rows
  const float* p = x_dbl + (size_t)row*80 + 48;
  float4 a = *(const float4*)(p);
  float4 b4 = *(const float4*)(p+4);
  float4 c4 = *(const float4*)(p+8);
  float4 d4 = *(const float4*)(p+12);
  float sm = a.x+a.y+a.z+a.w + b4.x+b4.y+b4.z+b4.w + c4.x+c4.y+c4.z+c4.w + d4.x+d4.y+d4.z+d4.w;
  float sq = a.x*a.x+a.y*a.y+a.z*a.z+a.w*a.w + b4.x*b4.x+b4.y*b4.y+b4.z*b4.z+b4.w*b4.w
           + c4.x*c4.x+c4.y*c4.y+c4.z*c4.z+c4.w*c4.w + d4.x*d4.x+d4.y*d4.y+d4.z*d4.z+d4.w*d4.w;
  float mB = sm * 0.0625f;
  float vB = fmaf(sq, 0.0625f, -(mB*mB));
  bs[row] = make_float2(mB, vB);
}

// ---------- K5: sequential selective-scan (writes raw yv only) ----------
// 16 lanes per (b,d) chain; lane = state index n (= output index h).
// All cross-lane via DPP. Matvec = Gray-code xor walk (transitions in {1,2,7,15}).
// 8-step double-buffered prefetch with stepped pointers; no tail branches
// (workspace is padded by WSPAD rows).
__global__ __launch_bounds__(64,1) void scan_kernel(const float* __restrict__ delta,
                                                    const float* __restrict__ uc,
                                                    const float* __restrict__ x_dbl,
                                                    const float2* __restrict__ bstat,
                                                    const float* __restrict__ A_log,
                                                    const float* __restrict__ Wq,
                                                    const float* __restrict__ Wk,
                                                    const float* __restrict__ Wv,
                                                    const float* __restrict__ g_s, const float* __restrict__ b_s,
                                                    const float* __restrict__ g_c, const float* __restrict__ b_c,
                                                    float* __restrict__ y){
  const int lane  = threadIdx.x & 15;
  const int chain = threadIdx.x >> 4;       // 0..3
  const int d = blockIdx.x * 4 + chain;     // grid.x = 384
  const int b = blockIdx.y;                 // grid.y = 2

  constexpr int gseq[16] = {0,1,3,2,5,4,6,7,8,9,11,10,13,12,14,15};
  float wq[16], wk[16], wv[16];
  #pragma unroll
  for (int i = 0; i < 16; i++){
    const int c = lane ^ gseq[i];
    wq[i] = Wq[lane*16 + c];
    wk[i] = Wk[lane*16 + c];
    wv[i] = Wv[lane*16 + c];
  }
  const float A_dn = -__expf(A_log[d*16 + lane]);
  const float gs = g_s[lane], bs0 = b_s[lane];
  const float gc = g_c[lane], bc0 = b_c[lane];

  const float* pd0 = delta + (size_t)b*LL*DI + d;
  const float* pd1 = pd0 + DI;
  const float* pd2 = pd0 + 2*DI;
  const float* pd3 = pd0 + 3*DI;
  const float* pu0 = uc + (size_t)b*LL*DI + d;
  const float* pu1 = pu0 + DI;
  const float* pu2 = pu0 + 2*DI;
  const float* pu3 = pu0 + 3*DI;
  const float* px0 = x_dbl + (size_t)b*LL*80 + 48 + lane;
  const float* px1 = px0 + 80;
  const float* px2 = px0 + 160;
  const float* px3 = px0 + 240;
  const float2* ps = bstat + (size_t)b*LL;
  float* py = y + (size_t)b*LL*DI + d;

  float s = 0.f;

  #define DECLH(P) float P##d0,P##u0,P##B0,P##C0,P##m0,P##v0, \
                         P##d1,P##u1,P##B1,P##C1,P##m1,P##v1, \
                         P##d2,P##u2,P##B2,P##C2,P##m2,P##v2, \
                         P##d3,P##u3,P##B3,P##C3,P##m3,P##v3;
  #define LOADH(P) { \
    P##d0=pd0[0]; P##d1=pd1[0]; P##d2=pd2[0]; P##d3=pd3[0]; \
    P##u0=pu0[0]; P##u1=pu1[0]; P##u2=pu2[0]; P##u3=pu3[0]; \
    P##B0=px0[0]; P##B1=px1[0]; P##B2=px2[0]; P##B3=px3[0]; \
    P##C0=px0[16]; P##C1=px1[16]; P##C2=px2[16]; P##C3=px3[16]; \
    float2 t0_=ps[0], t1_=ps[1], t2_=ps[2], t3_=ps[3]; \
    P##m0=t0_.x; P##v0=t0_.y; P##m1=t1_.x; P##v1=t1_.y; \
    P##m2=t2_.x; P##v2=t2_.y; P##m3=t3_.x; P##v3=t3_.y; \
    pd0+=4*DI; pd1+=4*DI; pd2+=4*DI; pd3+=4*DI; \
    pu0+=4*DI; pu1+=4*DI; pu2+=4*DI; pu3+=4*DI; \
    px0+=4*80; px1+=4*80; px2+=4*80; px3+=4*80; ps+=4; }

  #define MV(i, CTRL) { vs = DPPX(CTRL, vs); vc = DPPX(CTRL, vc); \
    qq = fmaf(vs, wq[i], qq); kk = fmaf(vc, wk[i], kk); vv = fmaf(vc, wv[i], vv); }

  #define STEP(dv,uv,Bv,Cv,mB,vB) { \
    const float alpha = (dv)*(uv); \
    const float dA = __expf((dv) * A_dn); \
    const float st = dA * s; \
    const float ssum = sum16(st); \
    const float ssq  = sum16(st*st); \
    const float m_s = ssum * 0.0625f; \
    const float v_s = fmaf(ssq, 0.0625f, -(m_s*m_s)); \
    const float k1 = rsqrtf(v_s + 1e-5f) * gs; \
    float vs = fmaf(st, k1, fmaf(-m_s, k1, bs0)); \
    const float rc = alpha * rsqrtf(fmaf(alpha*alpha, (vB), 1e-5f)); \
    const float k2 = rc * gc; \
    float vc = fmaf((Bv), k2, fmaf(-(mB), k2, bc0)); \
    float qq = vs*wq[0], kk = vc*wk[0], vv = vc*wv[0]; \
    MV(1,0xB1)  MV(2,0x4E)  MV(3,0xB1)  MV(4,0x141) \
    MV(5,0xB1)  MV(6,0x4E)  MV(7,0xB1)  MV(8,0x140) \
    MV(9,0xB1)  MV(10,0x4E) MV(11,0xB1) MV(12,0x141) \
    MV(13,0xB1) MV(14,0x4E) MV(15,0xB1) \
    const float wgt = sum16(qq*kk) * 0.25f; \
    const float nv = fmaf(wgt, vv - qq, qq); \
    s = nv; \
    const float yv = sum16(nv * (Cv)); \
    py[0] = yv; py += DI; \
  }

  DECLH(A) DECLH(B)
  LOADH(A)
  LOADH(B)
  for (int it = 0; it < LL/8; ++it){
    STEP(Ad0,Au0,AB0,AC0,Am0,Av0)
    STEP(Ad1,Au1,AB1,AC1,Am1,Av1)
    STEP(Ad2,Au2,AB2,AC2,Am2,Av2)
    STEP(Ad3,Au3,AB3,AC3,Am3,Av3)
    LOADH(A)
    STEP(Bd0,Bu0,BB0,BC0,Bm0,Bv0)
    STEP(Bd1,Bu1,BB1,BC1,Bm1,Bv1)
    STEP(Bd2,Bu2,BB2,BC2,Bm2,Bv2)
    STEP(Bd3,Bu3,BB3,BC3,Bm3,Bv3)
    LOADH(B)
  }
  #undef STEP
  #undef MV
  #undef LOADH
  #undef DECLH
}

// ---------- K5b: y = (yv + uc*Dp) * silu(res) ----------
__global__ __launch_bounds__(128) void ymerge_kernel(float* __restrict__ y,
                                                     const float* __restrict__ ucb,
                                                     const float* __restrict__ xr,
                                                     const float* __restrict__ Dp){
  const int kq = blockIdx.x*128 + threadIdx.x;  // 0..383 (quads per row)
  const int m  = blockIdx.y;                    // 0..2047
  const int k0 = kq*4;
  float4 yv = *(float4*)(y + (size_t)m*DI + k0);
  float4 u4 = *(const float4*)(ucb + (size_t)m*DI + k0);
  float4 D4 = *(const float4*)(Dp + k0);
  float4 r4 = *(const float4*)(xr + (size_t)m*(2*DI) + DI + k0);
  float4 o;
  o.x = fmaf(u4.x, D4.x, yv.x) * siluf_(r4.x);
  o.y = fmaf(u4.y, D4.y, yv.y) * siluf_(r4.y);
  o.z = fmaf(u4.z, D4.z, yv.z) * siluf_(r4.z);
  o.w = fmaf(u4.w, D4.w, yv.w) * siluf_(r4.w);
  *(float4*)(y + (size_t)m*DI + k0) = o;
}

// ---------- K6: LN(h)*(1+scale)+shift, then SiLU (in place) ----------
__global__ __launch_bounds__(256) void lnmod_kernel(float* __restrict__ h,
                                                    const float* __restrict__ g,
                                                    const float* __restrict__ bb,
                                                    const float* __restrict__ eo){
  const int row = blockIdx.x;
  const int b = row >> 10;
  float* hp = h + (size_t)row * DM;
  const int tid = threadIdx.x;
  float vals[3];
  float s1 = 0.f, s2 = 0.f;
  #pragma unroll
  for (int i = 0; i < 3; i++){ float v = hp[tid + i*256]; vals[i] = v; s1 += v; s2 += v*v; }
  #pragma unroll
  for (int off = 32; off; off >>= 1){ s1 += __shfl_xor(s1, off); s2 += __shfl_xor(s2, off); }
  __shared__ float wa[4], wb[4];
  if ((tid & 63) == 0){ wa[tid >> 6] = s1; wb[tid >> 6] = s2; }
  __syncthreads();
  s1 = wa[0] + wa[1] + wa[2] + wa[3];
  s2 = wb[0] + wb[1] + wb[2] + wb[3];
  const float m  = s1 * (1.f/768.f);
  const float var = s2 * (1.f/768.f) - m*m;
  const float rs = rsqrtf(var + 1e-5f);
  #pragma unroll
  for (int i = 0; i < 3; i++){
    const int j = tid + i*256;
    float h2 = (vals[i] - m)*rs*g[j] + bb[j];
    const float sc = eo[b*(2*DM) + j];
    const float sh = eo[b*(2*DM) + DM + j];
    h2 = h2*(1.f + sc) + sh;
    hp[j] = siluf_(h2);
  }
}

extern "C" void kernel_launch(void* const* d_in, const int* in_sizes, int n_in,
                              void* d_out, int out_size, void* d_ws, size_t ws_size,
                              hipStream_t stream){
  const float* x      = (const float*)d_in[0];
  const float* emb    = (const float*)d_in[1];
  const float* rms_w  = (const float*)d_in[2];
  const float* Win    = (const float*)d_in[3];
  const float* conv_w = (const float*)d_in[4];
  const float* conv_b = (const float*)d_in[5];
  const float* Wx     = (const float*)d_in[6];
  const float* Wdt    = (const float*)d_in[7];
  const float* bdt    = (const float*)d_in[8];
  const float* A_log  = (const float*)d_in[9];
  const float* Dp     = (const float*)d_in[10];
  const float* Wout   = (const float*)d_in[11];
  const float* Wq     = (const float*)d_in[12];
  const float* Wk     = (const float*)d_in[13];
  const float* Wv     = (const float*)d_in[14];
  const float* ln_s_g = (const float*)d_in[15];
  const float* ln_s_b = (const float*)d_in[16];
  const float* ln_c_g = (const float*)d_in[17];
  const float* ln_c_b = (const float*)d_in[18];
  const float* We     = (const float*)d_in[19];
  const float* be     = (const float*)d_in[20];
  const float* ln_h_g = (const float*)d_in[21];
  const float* ln_h_b = (const float*)d_in[22];
  const float* Wo     = (const float*)d_in[23];
  const float* bo     = (const float*)d_in[24];
  float* out = (float*)d_out;

  float* ws  = (float*)d_ws;
  float* xr  = ws;                                      // 2048*3072
  float* ucb = xr  + (size_t)2048*3072;                 // 2048*1536 (+pad)
  float* xdb = ucb + (size_t)(2048+WSPAD)*1536;         // 2048*80 (+pad)
  float* dlt = xdb + (size_t)(2048+WSPAD)*80;           // 2048*1536 (+pad)
  float* yb  = dlt + (size_t)(2048+WSPAD)*1536;         // 2048*1536
  float* xnh = yb  + (size_t)2048*1536;                 // 2048*768
  float* eo  = xnh + (size_t)2048*768;                  // 2*1536
  float2* bst = (float2*)(eo + (size_t)2*1536);         // 2048 (+pad) float2

  // emb path (independent)
  emb_kernel<<<24, 128, 0, stream>>>(emb, We, be, eo);
  // RMSNorm
  rmsnorm_kernel<<<2048, 256, 0, stream>>>(x, rms_w, xnh);
  // xr = xn @ Win^T   (2048 x 3072, K=768)
  gemm_nt<0><<<dim3(48, 32), 256, 0, stream>>>(xnh, DM, Win, DM, xr, 2*DI, 2*DI, DM, nullptr, nullptr);
  // uc = silu(causal depthwise conv(u) + cb)
  conv_silu_kernel<<<dim3(6, 2048), 256, 0, stream>>>(xr, conv_w, conv_b, ucb);
  // x_dbl = uc @ Wx^T  (2048 x 80, K=1536)
  gemm_nt<0><<<dim3(2, 32), 256, 0, stream>>>(ucb, DI, Wx, DI, xdb, 80, 80, DI, nullptr, nullptr);
  // Bm row-stats
  bstat_kernel<<<8, 256, 0, stream>>>(xdb, bst);
  // delta = softplus(x_dbl[:, :48] @ Wdt^T + bdt)  (2048 x 1536, K=48)
  gemm_nt<1><<<dim3(24, 32), 256, 0, stream>>>(xdb, 80, Wdt, DTR, dlt, DI, DI, DTR, bdt, nullptr);
  // sequential scan -> raw yv
  scan_kernel<<<dim3(384, 2), 64, 0, stream>>>(dlt, ucb, xdb, bst, A_log, Wq, Wk, Wv,
                                               ln_s_g, ln_s_b, ln_c_g, ln_c_b, yb);
  // y = (yv + uc*Dp) * silu(res)
  ymerge_kernel<<<dim3(3, 2048), 128, 0, stream>>>(yb, ucb, xr, Dp);
  // h = y @ Wout^T  (2048 x 768, K=1536)
  gemm_nt<0><<<dim3(12, 32), 256, 0, stream>>>(yb, DI, Wout, DI, xnh, DM, DM, DI, nullptr, nullptr);
  // h2 = LN(h)*(1+scale)+shift ; s2 = silu(h2)  (in-place)
  lnmod_kernel<<<2048, 256, 0, stream>>>(xnh, ln_h_g, ln_h_b, eo);
  // out = x + s2 @ Wo^T + bo
  gemm_nt<2><<<dim3(12, 32), 256, 0, stream>>>(xnh, DM, Wo, DM, out, DM, DM, DM, bo, x);
}